// Round 1
// baseline (12511.826 us; speedup 1.0000x reference)
//
#include <hip/hip_runtime.h>
#include <math.h>

#define BB 32
#define SS 400
#define TT 64
#define VV 32000
#define EE 256
#define HH 512

// ---------------------------------------------------------------------------
// LSTM step: one time-step for up to two independent "directions".
// grid = nDir*128 blocks, 256 threads.
// Per dir: 128 blocks = 64 col-groups (8 h-cols each) x 2 batch-halves (16 b).
// thread: bi = tid&15 (batch within half), qh = (tid>>4)&1 (gate pair), cp = tid>>5 (col 0..7)
// qh=0 computes gates i,f ; qh=1 computes g,o ; exchange via shfl_xor(16).
// K = 768: x-part (emb gather, 256) + h-part (512).
// ---------------------------------------------------------------------------
struct LstmDirArgs {
  const float* W_ih; const float* W_hh; const float* b_ih; const float* b_hh;
  const int* tok; int tok_stride; int tok_idx;
  const float* h_in; float* h_out; float* c;
  float* out_h; int out_stride;
};

__global__ __launch_bounds__(256) void lstm_step_kernel(
    const float* __restrict__ emb, LstmDirArgs A0, LstmDirArgs A1, int nblk)
{
  LstmDirArgs a = ((int)blockIdx.x < nblk) ? A0 : A1;
  int blk = (int)blockIdx.x % nblk;
  int b0 = (blk & 1) * 16;
  int c0 = (blk >> 1) * 8;
  __shared__ float xh[16][770];   // 770 stride: float2 reads conflict-free
  int tid = threadIdx.x;
  // stage x rows (emb gather)
  for (int i = tid; i < 16 * 256; i += 256) {
    int bi = i >> 8, e = i & 255;
    int tokid = a.tok[(b0 + bi) * a.tok_stride + a.tok_idx];
    xh[bi][e] = emb[(size_t)tokid * EE + e];
  }
  // stage h rows
  for (int i = tid; i < 16 * 512; i += 256) {
    int bi = i >> 9, k = i & 511;
    xh[bi][256 + k] = a.h_in[(b0 + bi) * HH + k];
  }
  __syncthreads();

  int bi = tid & 15;
  int qh = (tid >> 4) & 1;
  int cp = tid >> 5;
  int col = c0 + cp;
  int r0 = (2 * qh) * HH + col;
  int r1 = (2 * qh + 1) * HH + col;
  const float4* Wi0 = (const float4*)(a.W_ih + (size_t)r0 * EE);
  const float4* Wi1 = (const float4*)(a.W_ih + (size_t)r1 * EE);
  const float4* Wh0 = (const float4*)(a.W_hh + (size_t)r0 * HH);
  const float4* Wh1 = (const float4*)(a.W_hh + (size_t)r1 * HH);
  const float2* xr = (const float2*)&xh[bi][0];
  float acc0 = 0.f, acc1 = 0.f;
  #pragma unroll 8
  for (int k4 = 0; k4 < EE / 4; ++k4) {
    float4 w0 = Wi0[k4], w1 = Wi1[k4];
    float2 xa = xr[2 * k4], xb = xr[2 * k4 + 1];
    acc0 += xa.x * w0.x + xa.y * w0.y + xb.x * w0.z + xb.y * w0.w;
    acc1 += xa.x * w1.x + xa.y * w1.y + xb.x * w1.z + xb.y * w1.w;
  }
  const float2* hr = (const float2*)&xh[bi][256];
  #pragma unroll 8
  for (int k4 = 0; k4 < HH / 4; ++k4) {
    float4 w0 = Wh0[k4], w1 = Wh1[k4];
    float2 ha = hr[2 * k4], hb = hr[2 * k4 + 1];
    acc0 += ha.x * w0.x + ha.y * w0.y + hb.x * w0.z + hb.y * w0.w;
    acc1 += ha.x * w1.x + ha.y * w1.y + hb.x * w1.z + hb.y * w1.w;
  }
  float g0 = acc0 + a.b_ih[r0] + a.b_hh[r0];
  float g1 = acc1 + a.b_ih[r1] + a.b_hh[r1];
  float og0 = __shfl_xor(g0, 16);
  float og1 = __shfl_xor(g1, 16);
  if (qh == 0) {
    int b = b0 + bi;
    float iv = 1.f / (1.f + expf(-g0));
    float fv = 1.f / (1.f + expf(-g1));
    float gv = tanhf(og0);
    float ov = 1.f / (1.f + expf(-og1));
    float cold = a.c[b * HH + col];
    float cnew = fv * cold + iv * gv;
    float hnew = ov * tanhf(cnew);
    a.c[b * HH + col] = cnew;
    a.h_out[b * HH + col] = hnew;
    a.out_h[(size_t)b * a.out_stride + col] = hnew;
  }
}

// ---------------------------------------------------------------------------
// Generic C[M,N] = act(A[M,K] @ B[N,K]^T + bias). 64x64 tile, Kc=16, 4x4/thread.
// flags: 1 = tanh, 2 = remap output row m=(t*32+b) -> (b*TT + t) (for d_out)
// M,N multiples of 64; K multiple of 16.
// ---------------------------------------------------------------------------
__global__ __launch_bounds__(256) void gemm_tn_kernel(
    const float* __restrict__ A, const float* __restrict__ Bw,
    const float* __restrict__ bias, float* __restrict__ C,
    int M, int N, int K, int flags)
{
  __shared__ float As[16][68], Bs[16][68];
  int tid = threadIdx.x;
  int n0 = blockIdx.x * 64, m0 = blockIdx.y * 64;
  int lm = tid >> 2;
  int lk = (tid & 3) * 4;
  const float* Ap = A + (size_t)(m0 + lm) * K + lk;
  const float* Bp = Bw + (size_t)(n0 + lm) * K + lk;
  int tm = (tid & 15) * 4;
  int tn = (tid >> 4) * 4;
  float acc[4][4];
  #pragma unroll
  for (int i = 0; i < 4; ++i)
    #pragma unroll
    for (int j = 0; j < 4; ++j) acc[i][j] = 0.f;

  for (int kc = 0; kc < K; kc += 16) {
    float4 av = *(const float4*)(Ap + kc);
    float4 bv = *(const float4*)(Bp + kc);
    __syncthreads();
    As[lk + 0][lm] = av.x; As[lk + 1][lm] = av.y; As[lk + 2][lm] = av.z; As[lk + 3][lm] = av.w;
    Bs[lk + 0][lm] = bv.x; Bs[lk + 1][lm] = bv.y; Bs[lk + 2][lm] = bv.z; Bs[lk + 3][lm] = bv.w;
    __syncthreads();
    #pragma unroll
    for (int k = 0; k < 16; ++k) {
      float4 a4 = *(const float4*)&As[k][tm];
      float4 b4 = *(const float4*)&Bs[k][tn];
      acc[0][0] += a4.x * b4.x; acc[0][1] += a4.x * b4.y; acc[0][2] += a4.x * b4.z; acc[0][3] += a4.x * b4.w;
      acc[1][0] += a4.y * b4.x; acc[1][1] += a4.y * b4.y; acc[1][2] += a4.y * b4.z; acc[1][3] += a4.y * b4.w;
      acc[2][0] += a4.z * b4.x; acc[2][1] += a4.z * b4.y; acc[2][2] += a4.z * b4.z; acc[2][3] += a4.z * b4.w;
      acc[3][0] += a4.w * b4.x; acc[3][1] += a4.w * b4.y; acc[3][2] += a4.w * b4.z; acc[3][3] += a4.w * b4.w;
    }
  }
  float b0v = bias[n0 + tn + 0], b1v = bias[n0 + tn + 1];
  float b2v = bias[n0 + tn + 2], b3v = bias[n0 + tn + 3];
  #pragma unroll
  for (int i = 0; i < 4; ++i) {
    int m = m0 + tm + i;
    int row = (flags & 2) ? ((m & 31) * TT + (m >> 5)) : m;
    float4 v;
    v.x = acc[i][0] + b0v; v.y = acc[i][1] + b1v;
    v.z = acc[i][2] + b2v; v.w = acc[i][3] + b3v;
    if (flags & 1) { v.x = tanhf(v.x); v.y = tanhf(v.y); v.z = tanhf(v.z); v.w = tanhf(v.w); }
    *(float4*)(C + (size_t)row * N + n0 + tn) = v;
  }
}

// ---------------------------------------------------------------------------
// block reductions (256 threads = 4 waves)
// ---------------------------------------------------------------------------
__device__ __forceinline__ float bredMax(float v, float* red) {
  #pragma unroll
  for (int o = 32; o; o >>= 1) v = fmaxf(v, __shfl_xor(v, o));
  if ((threadIdx.x & 63) == 0) red[threadIdx.x >> 6] = v;
  __syncthreads();
  float r = fmaxf(fmaxf(red[0], red[1]), fmaxf(red[2], red[3]));
  __syncthreads();
  return r;
}
__device__ __forceinline__ float bredSum(float v, float* red) {
  #pragma unroll
  for (int o = 32; o; o >>= 1) v += __shfl_xor(v, o);
  if ((threadIdx.x & 63) == 0) red[threadIdx.x >> 6] = v;
  __syncthreads();
  float r = red[0] + red[1] + red[2] + red[3];
  __syncthreads();
  return r;
}

// ---------------------------------------------------------------------------
// Fused attention per (t,b): scores over s, masked softmax, context, and
// catbuf row = [context(1024) | h(512)].
// ---------------------------------------------------------------------------
__global__ __launch_bounds__(256) void attn_kernel(
    const float* __restrict__ keys, const float* __restrict__ enc,
    const float* __restrict__ dhall, const int* __restrict__ slen,
    float* __restrict__ catbuf)
{
  int t = blockIdx.x >> 5, b = blockIdx.x & 31;
  int tid = threadIdx.x;
  __shared__ float hrow[HH];
  __shared__ float wrow[SS];
  __shared__ float red[4];
  const float* hp = dhall + ((size_t)t * BB + b) * HH;
  for (int i = tid; i < HH; i += 256) hrow[i] = hp[i];
  __syncthreads();
  int len = slen[b];
  float sc0, sc1;
  {
    int s = tid;                      // always < SS (256 < 400)
    if (s < len) {
      const float4* kp = (const float4*)(keys + ((size_t)s * BB + b) * HH);
      float acc = 0.f;
      #pragma unroll 4
      for (int k4 = 0; k4 < HH / 4; ++k4) {
        float4 kv = kp[k4];
        float4 hv = *(const float4*)&hrow[k4 * 4];
        acc += kv.x * hv.x + kv.y * hv.y + kv.z * hv.z + kv.w * hv.w;
      }
      sc0 = acc;
    } else sc0 = -1e18f;
  }
  {
    int s = tid + 256;
    if (s < SS) {
      if (s < len) {
        const float4* kp = (const float4*)(keys + ((size_t)s * BB + b) * HH);
        float acc = 0.f;
        #pragma unroll 4
        for (int k4 = 0; k4 < HH / 4; ++k4) {
          float4 kv = kp[k4];
          float4 hv = *(const float4*)&hrow[k4 * 4];
          acc += kv.x * hv.x + kv.y * hv.y + kv.z * hv.z + kv.w * hv.w;
        }
        sc1 = acc;
      } else sc1 = -1e18f;
    } else sc1 = -3e38f;
  }
  float m = bredMax(fmaxf(sc0, sc1), red);
  float p0 = expf(sc0 - m);
  float p1 = (tid + 256 < SS) ? expf(sc1 - m) : 0.f;
  float ssum = bredSum(p0 + p1, red);
  float inv = 1.f / ssum;
  wrow[tid] = p0 * inv;
  if (tid + 256 < SS) wrow[tid + 256] = p1 * inv;
  __syncthreads();
  // context: 4 contiguous d per thread
  int d0 = tid * 4;
  float4 accv = {0.f, 0.f, 0.f, 0.f};
  for (int s = 0; s < SS; ++s) {
    float wv = wrow[s];
    float4 ev = *(const float4*)(enc + ((size_t)s * BB + b) * (2 * HH) + d0);
    accv.x += wv * ev.x; accv.y += wv * ev.y; accv.z += wv * ev.z; accv.w += wv * ev.w;
  }
  size_t cb = ((size_t)t * BB + b) * 1536;
  *(float4*)(catbuf + cb + d0) = accv;
  for (int i = tid; i < HH; i += 256) catbuf[cb + 1024 + i] = hrow[i];
}

// ---------------------------------------------------------------------------
// log-softmax over V per output row: pass 1 stats, pass 2 subtract
// ---------------------------------------------------------------------------
__global__ __launch_bounds__(256) void lse_kernel(
    const float* __restrict__ out, float* __restrict__ stats)
{
  int r = blockIdx.x;
  const float4* p = (const float4*)(out + (size_t)r * VV);
  __shared__ float red[4];
  int tid = threadIdx.x;
  float m = -3e38f;
  for (int j = tid; j < VV / 4; j += 256) {
    float4 v = p[j];
    m = fmaxf(m, fmaxf(fmaxf(v.x, v.y), fmaxf(v.z, v.w)));
  }
  m = bredMax(m, red);
  float s = 0.f;
  for (int j = tid; j < VV / 4; j += 256) {
    float4 v = p[j];
    s += expf(v.x - m) + expf(v.y - m) + expf(v.z - m) + expf(v.w - m);
  }
  s = bredSum(s, red);
  if (tid == 0) stats[r] = m + logf(s);
}

__global__ __launch_bounds__(256) void lsub_kernel(
    float* __restrict__ out, const float* __restrict__ stats)
{
  int r = blockIdx.x;
  float st = stats[r];
  float4* p = (float4*)(out + (size_t)r * VV);
  for (int j = threadIdx.x; j < VV / 4; j += 256) {
    float4 v = p[j];
    v.x -= st; v.y -= st; v.z -= st; v.w -= st;
    p[j] = v;
  }
}

// ---------------------------------------------------------------------------
// decoder initial state: dec_h = [hf,hb]@dec_h_W^T ; dec_c = [cf,cb]@dec_c_W^T
// ---------------------------------------------------------------------------
__global__ __launch_bounds__(256) void dec_init_kernel(
    const float* __restrict__ hf, const float* __restrict__ hb,
    const float* __restrict__ cf, const float* __restrict__ cb,
    const float* __restrict__ Wh, const float* __restrict__ Wc,
    float* __restrict__ dh, float* __restrict__ dc)
{
  int b = blockIdx.x;
  __shared__ float hcat[2 * HH], ccat[2 * HH];
  int tid = threadIdx.x;
  for (int i = tid; i < HH; i += 256) {
    hcat[i] = hf[b * HH + i]; hcat[HH + i] = hb[b * HH + i];
    ccat[i] = cf[b * HH + i]; ccat[HH + i] = cb[b * HH + i];
  }
  __syncthreads();
  for (int col = tid; col < HH; col += 256) {
    const float4* wh = (const float4*)(Wh + (size_t)col * (2 * HH));
    const float4* wc = (const float4*)(Wc + (size_t)col * (2 * HH));
    float ah = 0.f, ac = 0.f;
    #pragma unroll 4
    for (int k4 = 0; k4 < (2 * HH) / 4; ++k4) {
      float4 h4 = *(const float4*)&hcat[k4 * 4];
      float4 w4 = wh[k4];
      ah += h4.x * w4.x + h4.y * w4.y + h4.z * w4.z + h4.w * w4.w;
      float4 c4 = *(const float4*)&ccat[k4 * 4];
      float4 v4 = wc[k4];
      ac += c4.x * v4.x + c4.y * v4.y + c4.z * v4.z + c4.w * v4.w;
    }
    dh[b * HH + col] = ah;
    dc[b * HH + col] = ac;
  }
}

__global__ __launch_bounds__(256) void init_states_kernel(
    const float* __restrict__ ih, const float* __restrict__ ic,
    float* hf, float* cf, float* hb, float* cbuf)
{
  int i = blockIdx.x * 256 + threadIdx.x;
  if (i < BB * HH) {
    int j = i & (HH - 1);
    hf[i] = ih[j];      cf[i] = ic[j];
    hb[i] = ih[HH + j]; cbuf[i] = ic[HH + j];
  }
}

// ---------------------------------------------------------------------------
extern "C" void kernel_launch(void* const* d_in, const int* in_sizes, int n_in,
                              void* d_out, int out_size, void* d_ws, size_t ws_size,
                              hipStream_t stream)
{
  (void)in_sizes; (void)n_in; (void)out_size; (void)ws_size;
  const int*   src  = (const int*)d_in[0];
  const int*   slen = (const int*)d_in[1];
  const int*   tgt  = (const int*)d_in[2];
  const float* emb  = (const float*)d_in[3];
  const float* eWif = (const float*)d_in[4];
  const float* eWhf = (const float*)d_in[5];
  const float* ebif = (const float*)d_in[6];
  const float* ebhf = (const float*)d_in[7];
  const float* eWib = (const float*)d_in[8];
  const float* eWhb = (const float*)d_in[9];
  const float* ebib = (const float*)d_in[10];
  const float* ebhb = (const float*)d_in[11];
  const float* einh = (const float*)d_in[12];
  const float* einc = (const float*)d_in[13];
  const float* dhW  = (const float*)d_in[14];
  const float* dcW  = (const float*)d_in[15];
  const float* cWi  = (const float*)d_in[16];
  const float* cWh  = (const float*)d_in[17];
  const float* cbi  = (const float*)d_in[18];
  const float* cbh  = (const float*)d_in[19];
  const float* aW   = (const float*)d_in[20];
  const float* abv  = (const float*)d_in[21];
  const float* ccW  = (const float*)d_in[22];
  const float* ccbv = (const float*)d_in[23];
  const float* oW   = (const float*)d_in[24];
  const float* obv  = (const float*)d_in[25];
  float* out = (float*)d_out;
  float* ws  = (float*)d_ws;

  size_t off = 0;
  float* enc_outs = ws + off; off += (size_t)SS * BB * 1024;   // 13,107,200
  float* keys     = ws + off; off += (size_t)SS * BB * HH;     //  6,553,600
  float* dhall    = ws + off; off += (size_t)TT * BB * HH;     //  1,048,576
  float* catb     = ws + off; off += (size_t)TT * BB * 1536;   //  3,145,728
  float* ccv      = ws + off; off += (size_t)TT * BB * HH;     //  1,048,576
  float* hf0 = ws + off; off += BB * HH;
  float* hf1 = ws + off; off += BB * HH;
  float* hb0 = ws + off; off += BB * HH;
  float* hb1 = ws + off; off += BB * HH;
  float* cfb = ws + off; off += BB * HH;
  float* cbb = ws + off; off += BB * HH;
  float* dh0 = ws + off; off += BB * HH;
  float* dh1 = ws + off; off += BB * HH;
  float* dcb = ws + off; off += BB * HH;
  float* stats = ws + off; off += TT * BB;
  float* hfbuf[2] = {hf0, hf1};
  float* hbbuf[2] = {hb0, hb1};
  float* dhbuf[2] = {dh0, dh1};

  init_states_kernel<<<64, 256, 0, stream>>>(einh, einc, hf0, cfb, hb0, cbb);

  // encoder: 400 steps, both directions per launch
  for (int i = 0; i < SS; ++i) {
    LstmDirArgs af;
    af.W_ih = eWif; af.W_hh = eWhf; af.b_ih = ebif; af.b_hh = ebhf;
    af.tok = src; af.tok_stride = SS; af.tok_idx = i;
    af.h_in = hfbuf[i & 1]; af.h_out = hfbuf[(i + 1) & 1]; af.c = cfb;
    af.out_h = enc_outs + (size_t)i * BB * 1024; af.out_stride = 1024;
    int sb = SS - 1 - i;
    LstmDirArgs ab;
    ab.W_ih = eWib; ab.W_hh = eWhb; ab.b_ih = ebib; ab.b_hh = ebhb;
    ab.tok = src; ab.tok_stride = SS; ab.tok_idx = sb;
    ab.h_in = hbbuf[i & 1]; ab.h_out = hbbuf[(i + 1) & 1]; ab.c = cbb;
    ab.out_h = enc_outs + (size_t)sb * BB * 1024 + HH; ab.out_stride = 1024;
    lstm_step_kernel<<<256, 256, 0, stream>>>(emb, af, ab, 128);
  }

  // attention keys: (S*B,1024) @ attn_W^T -> (S*B,512)
  gemm_tn_kernel<<<dim3(HH / 64, (SS * BB) / 64), 256, 0, stream>>>(
      enc_outs, aW, abv, keys, SS * BB, HH, 1024, 0);

  dec_init_kernel<<<BB, 256, 0, stream>>>(hf0, hb0, cfb, cbb, dhW, dcW, dh0, dcb);

  // decoder LSTM: 64 steps
  for (int t = 0; t < TT; ++t) {
    LstmDirArgs ad;
    ad.W_ih = cWi; ad.W_hh = cWh; ad.b_ih = cbi; ad.b_hh = cbh;
    ad.tok = tgt; ad.tok_stride = TT; ad.tok_idx = t;
    ad.h_in = dhbuf[t & 1]; ad.h_out = dhbuf[(t + 1) & 1]; ad.c = dcb;
    ad.out_h = dhall + (size_t)t * BB * HH; ad.out_stride = HH;
    lstm_step_kernel<<<128, 256, 0, stream>>>(emb, ad, ad, 128);
  }

  // batched attention + catbuf
  attn_kernel<<<TT * BB, 256, 0, stream>>>(keys, enc_outs, dhall, slen, catb);

  // cc = tanh(catbuf @ concat_W^T + b)
  gemm_tn_kernel<<<dim3(HH / 64, (TT * BB) / 64), 256, 0, stream>>>(
      catb, ccW, ccbv, ccv, TT * BB, HH, 1536, 1);

  // logits_raw = cc @ out_W^T + out_b  -> d_out (rows remapped (t,b)->(b,t))
  gemm_tn_kernel<<<dim3(VV / 64, (TT * BB) / 64), 256, 0, stream>>>(
      ccv, oW, obv, out, TT * BB, VV, HH, 2);

  // log-softmax in place on d_out
  lse_kernel<<<TT * BB, 256, 0, stream>>>(out, stats);
  lsub_kernel<<<TT * BB, 256, 0, stream>>>(out, stats);
}

// Round 2
// 7478.564 us; speedup vs baseline: 1.6730x; 1.6730x over previous
//
#include <hip/hip_runtime.h>
#include <math.h>

#define BB 32
#define SS 400
#define TT 64
#define VV 32000
#define EE 256
#define HH 512

typedef __attribute__((ext_vector_type(4))) float f32x4;
typedef __attribute__((ext_vector_type(8))) short bf16x8t;

__device__ __forceinline__ ushort f2bf(float x) {
  uint u = __float_as_uint(x);
  return (ushort)((u + 0x7fffu + ((u >> 16) & 1u)) >> 16);
}
__device__ __forceinline__ float bf2f(ushort x) {
  return __uint_as_float(((uint)x) << 16);
}
__device__ __forceinline__ void gload_lds16(const ushort* g, ushort* l) {
  __builtin_amdgcn_global_load_lds(
      (const __attribute__((address_space(1))) void*)g,
      (__attribute__((address_space(3))) void*)l, 16, 0, 0);
}

// ---------------------------------------------------------------------------
// fp32 -> bf16 conversion (RNE), n multiple of 4
// ---------------------------------------------------------------------------
__global__ __launch_bounds__(256) void f2bf_kernel(
    const float* __restrict__ in, ushort* __restrict__ out, long n)
{
  long step = (long)gridDim.x * 256 * 4;
  for (long i = ((long)blockIdx.x * 256 + threadIdx.x) * 4; i < n; i += step) {
    float4 v = *(const float4*)(in + i);
    ushort4 o;
    o.x = f2bf(v.x); o.y = f2bf(v.y); o.z = f2bf(v.z); o.w = f2bf(v.w);
    *(ushort4*)(out + i) = o;
  }
}

// gather embedding rows (bf16) for all timesteps: row = s*32 + b <- emb[tok[b*L+s]]
__global__ __launch_bounds__(64) void gather_x_kernel(
    const ushort* __restrict__ emb_bf, const int* __restrict__ tok, int L,
    ushort* __restrict__ xout)
{
  int row = blockIdx.x;            // s*32 + b
  int b = row & 31, s = row >> 5;
  int t = tok[b * L + s];
  const uint2* src = (const uint2*)(emb_bf + (size_t)t * EE);
  uint2* dst = (uint2*)(xout + (size_t)row * EE);
  dst[threadIdx.x] = src[threadIdx.x];   // 64 thr x 8B = 512B = 256 ushorts
}

// combined biases: out[0:2048)=a1+a2, [2048:4096)=b1+b2, [4096:6144)=c1+c2
__global__ __launch_bounds__(256) void bias3_kernel(
    const float* a1, const float* a2, const float* b1, const float* b2,
    const float* c1, const float* c2, float* out)
{
  int i = blockIdx.x * 256 + threadIdx.x;
  if (i < 2048) out[i] = a1[i] + a2[i];
  else if (i < 4096) out[i] = b1[i - 2048] + b2[i - 2048];
  else if (i < 6144) out[i] = c1[i - 4096] + c2[i - 4096];
}

// ---------------------------------------------------------------------------
// bf16 MFMA GEMM: C[M,N] = act(A[M,K] @ B[N,K]^T + bias)
// 128x128 tile, BK=32, 4 waves (2x2 of 64x64), 16x16x32 MFMA.
// flags: 1=tanh, 2=row remap m=(t*32+b)->(b*TT+t), 4=bf16 output.
// M,N multiples of 128; K multiple of 32.
// ---------------------------------------------------------------------------
__global__ __launch_bounds__(256) void gemm_mfma_kernel(
    const ushort* __restrict__ A, const ushort* __restrict__ B,
    const float* __restrict__ bias, void* __restrict__ Cout,
    int M, int N, int K, int flags)
{
  __shared__ ushort Asub[128 * 32], Bsub[128 * 32];
  int tid = threadIdx.x;
  int w = tid >> 6, l = tid & 63;
  int n0 = blockIdx.x * 128, m0 = blockIdx.y * 128;
  int wm = w >> 1, wn = w & 1;

  // staging addresses: wave w stages rows [16*(2w+j), +16) of each tile, j=0,1
  int srow = 16 * 2 * w + (l >> 2);
  int scol = (l & 3) * 8;
  const ushort* Ar0 = A + (size_t)(m0 + srow) * K + scol;
  const ushort* Ar1 = Ar0 + (size_t)16 * K;
  const ushort* Br0 = B + (size_t)(n0 + srow) * K + scol;
  const ushort* Br1 = Br0 + (size_t)16 * K;
  ushort* ldsA0 = Asub + (2 * w) * 512;      // wave-uniform LDS bases
  ushort* ldsA1 = Asub + (2 * w + 1) * 512;
  ushort* ldsB0 = Bsub + (2 * w) * 512;
  ushort* ldsB1 = Bsub + (2 * w + 1) * 512;

  f32x4 acc[4][4];
  #pragma unroll
  for (int i = 0; i < 4; ++i)
    #pragma unroll
    for (int j = 0; j < 4; ++j)
      acc[i][j] = (f32x4){0.f, 0.f, 0.f, 0.f};

  int lr = l & 15, lkb = (l >> 4) * 8;

  for (int k0 = 0; k0 < K; k0 += 32) {
    gload_lds16(Ar0 + k0, ldsA0);
    gload_lds16(Ar1 + k0, ldsA1);
    gload_lds16(Br0 + k0, ldsB0);
    gload_lds16(Br1 + k0, ldsB1);
    __syncthreads();
    bf16x8t af[4], bf[4];
    #pragma unroll
    for (int mf = 0; mf < 4; ++mf)
      af[mf] = *(const bf16x8t*)&Asub[(wm * 64 + mf * 16 + lr) * 32 + lkb];
    #pragma unroll
    for (int nf = 0; nf < 4; ++nf)
      bf[nf] = *(const bf16x8t*)&Bsub[(wn * 64 + nf * 16 + lr) * 32 + lkb];
    #pragma unroll
    for (int mf = 0; mf < 4; ++mf)
      #pragma unroll
      for (int nf = 0; nf < 4; ++nf)
        acc[mf][nf] = __builtin_amdgcn_mfma_f32_16x16x32_bf16(
            af[mf], bf[nf], acc[mf][nf], 0, 0, 0);
    __syncthreads();
  }

  int lg = l >> 4;
  #pragma unroll
  for (int mf = 0; mf < 4; ++mf) {
    #pragma unroll
    for (int nf = 0; nf < 4; ++nf) {
      int n = n0 + wn * 64 + nf * 16 + lr;
      float bv = bias[n];
      #pragma unroll
      for (int r = 0; r < 4; ++r) {
        int m = m0 + wm * 64 + mf * 16 + lg * 4 + r;
        float v = acc[mf][nf][r] + bv;
        if (flags & 1) v = tanhf(v);
        int row = (flags & 2) ? ((m & 31) * TT + (m >> 5)) : m;
        if (flags & 4) ((ushort*)Cout)[(size_t)row * N + n] = f2bf(v);
        else           ((float*)Cout)[(size_t)row * N + n] = v;
      }
    }
  }
}

// ---------------------------------------------------------------------------
// x-hoisted LSTM step: g = h @ W_hh^T + xw (xw holds x@W_ih^T + b_ih + b_hh, bf16)
// grid = nDir*128 blocks x 256 thr. Per dir: 64 col-groups x 2 batch-halves.
// ---------------------------------------------------------------------------
struct LstmXArgs {
  const float* W_hh; const ushort* xw;     // xw: [32][2048] for this step
  const float* h_in; float* h_out; float* c;
  float* out_h; int out_stride;
};

__global__ __launch_bounds__(256) void lstm_stepx_kernel(
    LstmXArgs A0, LstmXArgs A1, int nblk)
{
  LstmXArgs a = ((int)blockIdx.x < nblk) ? A0 : A1;
  int blk = (int)blockIdx.x % nblk;
  int b0 = (blk & 1) * 16;
  int c0 = (blk >> 1) * 8;
  __shared__ float xh[16][516];
  int tid = threadIdx.x;
  for (int i = tid; i < 16 * 128; i += 256) {   // 16 rows x 128 float4
    int bi = i >> 7, k = (i & 127) * 4;
    *(float4*)&xh[bi][k] = *(const float4*)(a.h_in + (size_t)(b0 + bi) * HH + k);
  }
  __syncthreads();

  int bi = tid & 15;
  int qh = (tid >> 4) & 1;
  int cp = tid >> 5;
  int col = c0 + cp;
  int r0 = (2 * qh) * HH + col;
  int r1 = (2 * qh + 1) * HH + col;
  const float4* Wh0 = (const float4*)(a.W_hh + (size_t)r0 * HH);
  const float4* Wh1 = (const float4*)(a.W_hh + (size_t)r1 * HH);
  const float4* hr = (const float4*)&xh[bi][0];
  float acc0 = 0.f, acc1 = 0.f;
  #pragma unroll 8
  for (int k4 = 0; k4 < HH / 4; ++k4) {
    float4 w0 = Wh0[k4], w1 = Wh1[k4];
    float4 hv = hr[k4];
    acc0 += hv.x * w0.x + hv.y * w0.y + hv.z * w0.z + hv.w * w0.w;
    acc1 += hv.x * w1.x + hv.y * w1.y + hv.z * w1.z + hv.w * w1.w;
  }
  float g0 = acc0 + bf2f(a.xw[(size_t)(b0 + bi) * 2048 + r0]);
  float g1 = acc1 + bf2f(a.xw[(size_t)(b0 + bi) * 2048 + r1]);
  float og0 = __shfl_xor(g0, 16);
  float og1 = __shfl_xor(g1, 16);
  if (qh == 0) {
    int b = b0 + bi;
    float iv = 1.f / (1.f + expf(-g0));
    float fv = 1.f / (1.f + expf(-g1));
    float gv = tanhf(og0);
    float ov = 1.f / (1.f + expf(-og1));
    float cold = a.c[b * HH + col];
    float cnew = fv * cold + iv * gv;
    float hnew = ov * tanhf(cnew);
    a.c[b * HH + col] = cnew;
    a.h_out[b * HH + col] = hnew;
    a.out_h[(size_t)b * a.out_stride + col] = hnew;
  }
}

// ---------------------------------------------------------------------------
// Legacy (fallback) LSTM step with inline emb gather, K=768
// ---------------------------------------------------------------------------
struct LstmDirArgs {
  const float* W_ih; const float* W_hh; const float* b_ih; const float* b_hh;
  const int* tok; int tok_stride; int tok_idx;
  const float* h_in; float* h_out; float* c;
  float* out_h; int out_stride;
};

__global__ __launch_bounds__(256) void lstm_step_kernel(
    const float* __restrict__ emb, LstmDirArgs A0, LstmDirArgs A1, int nblk)
{
  LstmDirArgs a = ((int)blockIdx.x < nblk) ? A0 : A1;
  int blk = (int)blockIdx.x % nblk;
  int b0 = (blk & 1) * 16;
  int c0 = (blk >> 1) * 8;
  __shared__ float xh[16][770];
  int tid = threadIdx.x;
  for (int i = tid; i < 16 * 256; i += 256) {
    int bi = i >> 8, e = i & 255;
    int tokid = a.tok[(b0 + bi) * a.tok_stride + a.tok_idx];
    xh[bi][e] = emb[(size_t)tokid * EE + e];
  }
  for (int i = tid; i < 16 * 512; i += 256) {
    int bi = i >> 9, k = i & 511;
    xh[bi][256 + k] = a.h_in[(b0 + bi) * HH + k];
  }
  __syncthreads();

  int bi = tid & 15;
  int qh = (tid >> 4) & 1;
  int cp = tid >> 5;
  int col = c0 + cp;
  int r0 = (2 * qh) * HH + col;
  int r1 = (2 * qh + 1) * HH + col;
  const float4* Wi0 = (const float4*)(a.W_ih + (size_t)r0 * EE);
  const float4* Wi1 = (const float4*)(a.W_ih + (size_t)r1 * EE);
  const float4* Wh0 = (const float4*)(a.W_hh + (size_t)r0 * HH);
  const float4* Wh1 = (const float4*)(a.W_hh + (size_t)r1 * HH);
  const float2* xr = (const float2*)&xh[bi][0];
  float acc0 = 0.f, acc1 = 0.f;
  #pragma unroll 8
  for (int k4 = 0; k4 < EE / 4; ++k4) {
    float4 w0 = Wi0[k4], w1 = Wi1[k4];
    float2 xa = xr[2 * k4], xb = xr[2 * k4 + 1];
    acc0 += xa.x * w0.x + xa.y * w0.y + xb.x * w0.z + xb.y * w0.w;
    acc1 += xa.x * w1.x + xa.y * w1.y + xb.x * w1.z + xb.y * w1.w;
  }
  const float2* hr = (const float2*)&xh[bi][256];
  #pragma unroll 8
  for (int k4 = 0; k4 < HH / 4; ++k4) {
    float4 w0 = Wh0[k4], w1 = Wh1[k4];
    float2 ha = hr[2 * k4], hb = hr[2 * k4 + 1];
    acc0 += ha.x * w0.x + ha.y * w0.y + hb.x * w0.z + hb.y * w0.w;
    acc1 += ha.x * w1.x + ha.y * w1.y + hb.x * w1.z + hb.y * w1.w;
  }
  float g0 = acc0 + a.b_ih[r0] + a.b_hh[r0];
  float g1 = acc1 + a.b_ih[r1] + a.b_hh[r1];
  float og0 = __shfl_xor(g0, 16);
  float og1 = __shfl_xor(g1, 16);
  if (qh == 0) {
    int b = b0 + bi;
    float iv = 1.f / (1.f + expf(-g0));
    float fv = 1.f / (1.f + expf(-g1));
    float gv = tanhf(og0);
    float ov = 1.f / (1.f + expf(-og1));
    float cold = a.c[b * HH + col];
    float cnew = fv * cold + iv * gv;
    float hnew = ov * tanhf(cnew);
    a.c[b * HH + col] = cnew;
    a.h_out[b * HH + col] = hnew;
    a.out_h[(size_t)b * a.out_stride + col] = hnew;
  }
}

// ---------------------------------------------------------------------------
// fp32 SMEM GEMM (fallback): C[M,N] = act(A[M,K] @ B[N,K]^T + bias)
// ---------------------------------------------------------------------------
__global__ __launch_bounds__(256) void gemm_tn_kernel(
    const float* __restrict__ A, const float* __restrict__ Bw,
    const float* __restrict__ bias, float* __restrict__ C,
    int M, int N, int K, int flags)
{
  __shared__ float As[16][68], Bs[16][68];
  int tid = threadIdx.x;
  int n0 = blockIdx.x * 64, m0 = blockIdx.y * 64;
  int lm = tid >> 2;
  int lk = (tid & 3) * 4;
  const float* Ap = A + (size_t)(m0 + lm) * K + lk;
  const float* Bp = Bw + (size_t)(n0 + lm) * K + lk;
  int tm = (tid & 15) * 4;
  int tn = (tid >> 4) * 4;
  float acc[4][4];
  #pragma unroll
  for (int i = 0; i < 4; ++i)
    #pragma unroll
    for (int j = 0; j < 4; ++j) acc[i][j] = 0.f;

  for (int kc = 0; kc < K; kc += 16) {
    float4 av = *(const float4*)(Ap + kc);
    float4 bv = *(const float4*)(Bp + kc);
    __syncthreads();
    As[lk + 0][lm] = av.x; As[lk + 1][lm] = av.y; As[lk + 2][lm] = av.z; As[lk + 3][lm] = av.w;
    Bs[lk + 0][lm] = bv.x; Bs[lk + 1][lm] = bv.y; Bs[lk + 2][lm] = bv.z; Bs[lk + 3][lm] = bv.w;
    __syncthreads();
    #pragma unroll
    for (int k = 0; k < 16; ++k) {
      float4 a4 = *(const float4*)&As[k][tm];
      float4 b4 = *(const float4*)&Bs[k][tn];
      acc[0][0] += a4.x * b4.x; acc[0][1] += a4.x * b4.y; acc[0][2] += a4.x * b4.z; acc[0][3] += a4.x * b4.w;
      acc[1][0] += a4.y * b4.x; acc[1][1] += a4.y * b4.y; acc[1][2] += a4.y * b4.z; acc[1][3] += a4.y * b4.w;
      acc[2][0] += a4.z * b4.x; acc[2][1] += a4.z * b4.y; acc[2][2] += a4.z * b4.z; acc[2][3] += a4.z * b4.w;
      acc[3][0] += a4.w * b4.x; acc[3][1] += a4.w * b4.y; acc[3][2] += a4.w * b4.z; acc[3][3] += a4.w * b4.w;
    }
  }
  float b0v = bias[n0 + tn + 0], b1v = bias[n0 + tn + 1];
  float b2v = bias[n0 + tn + 2], b3v = bias[n0 + tn + 3];
  #pragma unroll
  for (int i = 0; i < 4; ++i) {
    int m = m0 + tm + i;
    int row = (flags & 2) ? ((m & 31) * TT + (m >> 5)) : m;
    float4 v;
    v.x = acc[i][0] + b0v; v.y = acc[i][1] + b1v;
    v.z = acc[i][2] + b2v; v.w = acc[i][3] + b3v;
    if (flags & 1) { v.x = tanhf(v.x); v.y = tanhf(v.y); v.z = tanhf(v.z); v.w = tanhf(v.w); }
    *(float4*)(C + (size_t)row * N + n0 + tn) = v;
  }
}

// ---------------------------------------------------------------------------
__device__ __forceinline__ float bredMax(float v, float* red) {
  #pragma unroll
  for (int o = 32; o; o >>= 1) v = fmaxf(v, __shfl_xor(v, o));
  if ((threadIdx.x & 63) == 0) red[threadIdx.x >> 6] = v;
  __syncthreads();
  float r = fmaxf(fmaxf(red[0], red[1]), fmaxf(red[2], red[3]));
  __syncthreads();
  return r;
}
__device__ __forceinline__ float bredSum(float v, float* red) {
  #pragma unroll
  for (int o = 32; o; o >>= 1) v += __shfl_xor(v, o);
  if ((threadIdx.x & 63) == 0) red[threadIdx.x >> 6] = v;
  __syncthreads();
  float r = red[0] + red[1] + red[2] + red[3];
  __syncthreads();
  return r;
}

// ---------------------------------------------------------------------------
// Fused attention per (t,b). obf: 1 -> catbuf is bf16 (ushort), 0 -> fp32.
// ---------------------------------------------------------------------------
__global__ __launch_bounds__(256) void attn_kernel(
    const float* __restrict__ keys, const float* __restrict__ enc,
    const float* __restrict__ dhall, const int* __restrict__ slen,
    void* __restrict__ catbuf, int obf)
{
  int t = blockIdx.x >> 5, b = blockIdx.x & 31;
  int tid = threadIdx.x;
  __shared__ float hrow[HH];
  __shared__ float wrow[SS];
  __shared__ float red[4];
  const float* hp = dhall + ((size_t)t * BB + b) * HH;
  for (int i = tid; i < HH; i += 256) hrow[i] = hp[i];
  __syncthreads();
  int len = slen[b];
  float sc0, sc1;
  {
    int s = tid;
    if (s < len) {
      const float4* kp = (const float4*)(keys + ((size_t)s * BB + b) * HH);
      float acc = 0.f;
      #pragma unroll 4
      for (int k4 = 0; k4 < HH / 4; ++k4) {
        float4 kv = kp[k4];
        float4 hv = *(const float4*)&hrow[k4 * 4];
        acc += kv.x * hv.x + kv.y * hv.y + kv.z * hv.z + kv.w * hv.w;
      }
      sc0 = acc;
    } else sc0 = -1e18f;
  }
  {
    int s = tid + 256;
    if (s < SS) {
      if (s < len) {
        const float4* kp = (const float4*)(keys + ((size_t)s * BB + b) * HH);
        float acc = 0.f;
        #pragma unroll 4
        for (int k4 = 0; k4 < HH / 4; ++k4) {
          float4 kv = kp[k4];
          float4 hv = *(const float4*)&hrow[k4 * 4];
          acc += kv.x * hv.x + kv.y * hv.y + kv.z * hv.z + kv.w * hv.w;
        }
        sc1 = acc;
      } else sc1 = -1e18f;
    } else sc1 = -3e38f;
  }
  float m = bredMax(fmaxf(sc0, sc1), red);
  float p0 = expf(sc0 - m);
  float p1 = (tid + 256 < SS) ? expf(sc1 - m) : 0.f;
  float ssum = bredSum(p0 + p1, red);
  float inv = 1.f / ssum;
  wrow[tid] = p0 * inv;
  if (tid + 256 < SS) wrow[tid + 256] = p1 * inv;
  __syncthreads();
  int d0 = tid * 4;
  float4 accv = {0.f, 0.f, 0.f, 0.f};
  for (int s = 0; s < SS; ++s) {
    float wv = wrow[s];
    float4 ev = *(const float4*)(enc + ((size_t)s * BB + b) * (2 * HH) + d0);
    accv.x += wv * ev.x; accv.y += wv * ev.y; accv.z += wv * ev.z; accv.w += wv * ev.w;
  }
  size_t cb = ((size_t)t * BB + b) * 1536;
  if (obf) {
    ushort* cp = (ushort*)catbuf;
    ushort4 o;
    o.x = f2bf(accv.x); o.y = f2bf(accv.y); o.z = f2bf(accv.z); o.w = f2bf(accv.w);
    *(ushort4*)(cp + cb + d0) = o;
    for (int i = tid; i < HH; i += 256) cp[cb + 1024 + i] = f2bf(hrow[i]);
  } else {
    float* cp = (float*)catbuf;
    *(float4*)(cp + cb + d0) = accv;
    for (int i = tid; i < HH; i += 256) cp[cb + 1024 + i] = hrow[i];
  }
}

// ---------------------------------------------------------------------------
__global__ __launch_bounds__(256) void lse_kernel(
    const float* __restrict__ out, float* __restrict__ stats)
{
  int r = blockIdx.x;
  const float4* p = (const float4*)(out + (size_t)r * VV);
  __shared__ float red[4];
  int tid = threadIdx.x;
  float m = -3e38f;
  for (int j = tid; j < VV / 4; j += 256) {
    float4 v = p[j];
    m = fmaxf(m, fmaxf(fmaxf(v.x, v.y), fmaxf(v.z, v.w)));
  }
  m = bredMax(m, red);
  float s = 0.f;
  for (int j = tid; j < VV / 4; j += 256) {
    float4 v = p[j];
    s += expf(v.x - m) + expf(v.y - m) + expf(v.z - m) + expf(v.w - m);
  }
  s = bredSum(s, red);
  if (tid == 0) stats[r] = m + logf(s);
}

__global__ __launch_bounds__(256) void lsub_kernel(
    float* __restrict__ out, const float* __restrict__ stats)
{
  int r = blockIdx.x;
  float st = stats[r];
  float4* p = (float4*)(out + (size_t)r * VV);
  for (int j = threadIdx.x; j < VV / 4; j += 256) {
    float4 v = p[j];
    v.x -= st; v.y -= st; v.z -= st; v.w -= st;
    p[j] = v;
  }
}

// ---------------------------------------------------------------------------
__global__ __launch_bounds__(256) void dec_init_kernel(
    const float* __restrict__ hf, const float* __restrict__ hb,
    const float* __restrict__ cf, const float* __restrict__ cb,
    const float* __restrict__ Wh, const float* __restrict__ Wc,
    float* __restrict__ dh, float* __restrict__ dc)
{
  int b = blockIdx.x;
  __shared__ float hcat[2 * HH], ccat[2 * HH];
  int tid = threadIdx.x;
  for (int i = tid; i < HH; i += 256) {
    hcat[i] = hf[b * HH + i]; hcat[HH + i] = hb[b * HH + i];
    ccat[i] = cf[b * HH + i]; ccat[HH + i] = cb[b * HH + i];
  }
  __syncthreads();
  for (int col = tid; col < HH; col += 256) {
    const float4* wh = (const float4*)(Wh + (size_t)col * (2 * HH));
    const float4* wc = (const float4*)(Wc + (size_t)col * (2 * HH));
    float ah = 0.f, ac = 0.f;
    #pragma unroll 4
    for (int k4 = 0; k4 < (2 * HH) / 4; ++k4) {
      float4 h4 = *(const float4*)&hcat[k4 * 4];
      float4 w4 = wh[k4];
      ah += h4.x * w4.x + h4.y * w4.y + h4.z * w4.z + h4.w * w4.w;
      float4 c4 = *(const float4*)&ccat[k4 * 4];
      float4 v4 = wc[k4];
      ac += c4.x * v4.x + c4.y * v4.y + c4.z * v4.z + c4.w * v4.w;
    }
    dh[b * HH + col] = ah;
    dc[b * HH + col] = ac;
  }
}

__global__ __launch_bounds__(256) void init_states_kernel(
    const float* __restrict__ ih, const float* __restrict__ ic,
    float* hf, float* cf, float* hb, float* cbuf)
{
  int i = blockIdx.x * 256 + threadIdx.x;
  if (i < BB * HH) {
    int j = i & (HH - 1);
    hf[i] = ih[j];      cf[i] = ic[j];
    hb[i] = ih[HH + j]; cbuf[i] = ic[HH + j];
  }
}

// ---------------------------------------------------------------------------
extern "C" void kernel_launch(void* const* d_in, const int* in_sizes, int n_in,
                              void* d_out, int out_size, void* d_ws, size_t ws_size,
                              hipStream_t stream)
{
  (void)in_sizes; (void)n_in; (void)out_size;
  const int*   src  = (const int*)d_in[0];
  const int*   slen = (const int*)d_in[1];
  const int*   tgt  = (const int*)d_in[2];
  const float* emb  = (const float*)d_in[3];
  const float* eWif = (const float*)d_in[4];
  const float* eWhf = (const float*)d_in[5];
  const float* ebif = (const float*)d_in[6];
  const float* ebhf = (const float*)d_in[7];
  const float* eWib = (const float*)d_in[8];
  const float* eWhb = (const float*)d_in[9];
  const float* ebib = (const float*)d_in[10];
  const float* ebhb = (const float*)d_in[11];
  const float* einh = (const float*)d_in[12];
  const float* einc = (const float*)d_in[13];
  const float* dhW  = (const float*)d_in[14];
  const float* dcW  = (const float*)d_in[15];
  const float* cWi  = (const float*)d_in[16];
  const float* cWh  = (const float*)d_in[17];
  const float* cbi  = (const float*)d_in[18];
  const float* cbh  = (const float*)d_in[19];
  const float* aW   = (const float*)d_in[20];
  const float* abv  = (const float*)d_in[21];
  const float* ccW  = (const float*)d_in[22];
  const float* ccbv = (const float*)d_in[23];
  const float* oW   = (const float*)d_in[24];
  const float* obv  = (const float*)d_in[25];
  float* out = (float*)d_out;
  float* ws  = (float*)d_ws;

  // ---------- full-path workspace layout (floats) ----------
  size_t off = 0;
  float* enc_outs = ws + off; off += (size_t)SS * BB * 1024;
  float* keys     = ws + off; off += (size_t)SS * BB * HH;
  float* dhall    = ws + off; off += (size_t)TT * BB * HH;
  ushort* catb_bf = (ushort*)(ws + off); off += (size_t)TT * BB * 1536 / 2;
  ushort* ccv_bf  = (ushort*)(ws + off); off += (size_t)TT * BB * HH / 2;
  float* stats = ws + off; off += TT * BB;
  float* hf0 = ws + off; off += BB * HH;
  float* hf1 = ws + off; off += BB * HH;
  float* hb0 = ws + off; off += BB * HH;
  float* hb1 = ws + off; off += BB * HH;
  float* cfb = ws + off; off += BB * HH;
  float* cbb = ws + off; off += BB * HH;
  float* dh0 = ws + off; off += BB * HH;
  float* dh1 = ws + off; off += BB * HH;
  float* dcb = ws + off; off += BB * HH;
  float* bias3 = ws + off; off += 3 * 2048;
  ushort* emb_bf = (ushort*)(ws + off); off += (size_t)VV * EE / 2;
  ushort* xe_bf  = (ushort*)(ws + off); off += (size_t)SS * BB * EE / 2;
  ushort* xd_bf  = (ushort*)(ws + off); off += (size_t)TT * BB * EE / 2;
  ushort* xWf_bf = (ushort*)(ws + off); off += (size_t)SS * BB * 2048 / 2;
  ushort* xWb_bf = (ushort*)(ws + off); off += (size_t)SS * BB * 2048 / 2;
  ushort* xWd_bf = (ushort*)(ws + off); off += (size_t)TT * BB * 2048 / 2;
  ushort* encA_bf = (ushort*)(ws + off); off += (size_t)SS * BB * 1024 / 2;
  ushort* oW_bf  = (ushort*)(ws + off); off += (size_t)VV * HH / 2;
  ushort* aW_bf  = (ushort*)(ws + off); off += (size_t)HH * 1024 / 2;
  ushort* ccW_bf = (ushort*)(ws + off); off += (size_t)HH * 1536 / 2;
  ushort* eWif_bf = (ushort*)(ws + off); off += (size_t)2048 * EE / 2;
  ushort* eWib_bf = (ushort*)(ws + off); off += (size_t)2048 * EE / 2;
  ushort* cWi_bf  = (ushort*)(ws + off); off += (size_t)2048 * EE / 2;
  size_t needBytes = off * sizeof(float);

  float* hfbuf[2] = {hf0, hf1};
  float* hbbuf[2] = {hb0, hb1};
  float* dhbuf[2] = {dh0, dh1};

  if (ws_size >= needBytes) {
    // ======================= FULL (MFMA + x-hoist) PATH =======================
    init_states_kernel<<<64, 256, 0, stream>>>(einh, einc, hf0, cfb, hb0, cbb);

    // bf16 conversions
    f2bf_kernel<<<4096, 256, 0, stream>>>(emb, emb_bf, (long)VV * EE);
    f2bf_kernel<<<2048, 256, 0, stream>>>(oW, oW_bf, (long)VV * HH);
    f2bf_kernel<<<512, 256, 0, stream>>>(aW, aW_bf, (long)HH * 1024);
    f2bf_kernel<<<512, 256, 0, stream>>>(ccW, ccW_bf, (long)HH * 1536);
    f2bf_kernel<<<512, 256, 0, stream>>>(eWif, eWif_bf, (long)2048 * EE);
    f2bf_kernel<<<512, 256, 0, stream>>>(eWib, eWib_bf, (long)2048 * EE);
    f2bf_kernel<<<512, 256, 0, stream>>>(cWi, cWi_bf, (long)2048 * EE);
    bias3_kernel<<<24, 256, 0, stream>>>(ebif, ebhf, ebib, ebhb, cbi, cbh, bias3);

    // gather x rows
    gather_x_kernel<<<SS * BB, 64, 0, stream>>>(emb_bf, src, SS, xe_bf);
    gather_x_kernel<<<TT * BB, 64, 0, stream>>>(emb_bf, tgt, TT, xd_bf);

    // x-part GEMMs (bias folded, bf16 out)
    gemm_mfma_kernel<<<dim3(2048 / 128, (SS * BB) / 128), 256, 0, stream>>>(
        xe_bf, eWif_bf, bias3, xWf_bf, SS * BB, 2048, EE, 4);
    gemm_mfma_kernel<<<dim3(2048 / 128, (SS * BB) / 128), 256, 0, stream>>>(
        xe_bf, eWib_bf, bias3 + 2048, xWb_bf, SS * BB, 2048, EE, 4);
    gemm_mfma_kernel<<<dim3(2048 / 128, (TT * BB) / 128), 256, 0, stream>>>(
        xd_bf, cWi_bf, bias3 + 4096, xWd_bf, TT * BB, 2048, EE, 4);

    // encoder: 400 steps, both directions per launch
    for (int i = 0; i < SS; ++i) {
      LstmXArgs af;
      af.W_hh = eWhf; af.xw = xWf_bf + (size_t)i * BB * 2048;
      af.h_in = hfbuf[i & 1]; af.h_out = hfbuf[(i + 1) & 1]; af.c = cfb;
      af.out_h = enc_outs + (size_t)i * BB * 1024; af.out_stride = 1024;
      int sb = SS - 1 - i;
      LstmXArgs ab;
      ab.W_hh = eWhb; ab.xw = xWb_bf + (size_t)sb * BB * 2048;
      ab.h_in = hbbuf[i & 1]; ab.h_out = hbbuf[(i + 1) & 1]; ab.c = cbb;
      ab.out_h = enc_outs + (size_t)sb * BB * 1024 + HH; ab.out_stride = 1024;
      lstm_stepx_kernel<<<256, 256, 0, stream>>>(af, ab, 128);
    }

    dec_init_kernel<<<BB, 256, 0, stream>>>(hf0, hb0, cfb, cbb, dhW, dcW, dh0, dcb);

    // decoder LSTM: 64 steps
    for (int t = 0; t < TT; ++t) {
      LstmXArgs ad;
      ad.W_hh = cWh; ad.xw = xWd_bf + (size_t)t * BB * 2048;
      ad.h_in = dhbuf[t & 1]; ad.h_out = dhbuf[(t + 1) & 1]; ad.c = dcb;
      ad.out_h = dhall + (size_t)t * BB * HH; ad.out_stride = HH;
      lstm_stepx_kernel<<<128, 256, 0, stream>>>(ad, ad, 128);
    }

    // attention keys GEMM (A = enc_outs bf16)
    f2bf_kernel<<<4096, 256, 0, stream>>>(enc_outs, encA_bf, (long)SS * BB * 1024);
    gemm_mfma_kernel<<<dim3(HH / 128, (SS * BB) / 128), 256, 0, stream>>>(
        encA_bf, aW_bf, abv, keys, SS * BB, HH, 1024, 0);

    attn_kernel<<<TT * BB, 256, 0, stream>>>(keys, enc_outs, dhall, slen, catb_bf, 1);

    gemm_mfma_kernel<<<dim3(HH / 128, (TT * BB) / 128), 256, 0, stream>>>(
        catb_bf, ccW_bf, ccbv, ccv_bf, TT * BB, HH, 1536, 1 | 4);

    gemm_mfma_kernel<<<dim3(VV / 128, (TT * BB) / 128), 256, 0, stream>>>(
        ccv_bf, oW_bf, obv, out, TT * BB, VV, HH, 2);

    lse_kernel<<<TT * BB, 256, 0, stream>>>(out, stats);
    lsub_kernel<<<TT * BB, 256, 0, stream>>>(out, stats);
  } else {
    // ======================= FALLBACK (R1) PATH =======================
    size_t o2 = 0;
    float* enc_outs2 = ws + o2; o2 += (size_t)SS * BB * 1024;
    float* keys2     = ws + o2; o2 += (size_t)SS * BB * HH;
    float* dhall2    = ws + o2; o2 += (size_t)TT * BB * HH;
    float* catb2     = ws + o2; o2 += (size_t)TT * BB * 1536;
    float* ccv2      = ws + o2; o2 += (size_t)TT * BB * HH;
    float* hf0b = ws + o2; o2 += BB * HH;
    float* hf1b = ws + o2; o2 += BB * HH;
    float* hb0b = ws + o2; o2 += BB * HH;
    float* hb1b = ws + o2; o2 += BB * HH;
    float* cfb2 = ws + o2; o2 += BB * HH;
    float* cbb2 = ws + o2; o2 += BB * HH;
    float* dh0b = ws + o2; o2 += BB * HH;
    float* dh1b = ws + o2; o2 += BB * HH;
    float* dcb2 = ws + o2; o2 += BB * HH;
    float* stats2 = ws + o2; o2 += TT * BB;
    float* hfb[2] = {hf0b, hf1b};
    float* hbb[2] = {hb0b, hb1b};
    float* dhb[2] = {dh0b, dh1b};

    init_states_kernel<<<64, 256, 0, stream>>>(einh, einc, hf0b, cfb2, hb0b, cbb2);

    for (int i = 0; i < SS; ++i) {
      LstmDirArgs af;
      af.W_ih = eWif; af.W_hh = eWhf; af.b_ih = ebif; af.b_hh = ebhf;
      af.tok = src; af.tok_stride = SS; af.tok_idx = i;
      af.h_in = hfb[i & 1]; af.h_out = hfb[(i + 1) & 1]; af.c = cfb2;
      af.out_h = enc_outs2 + (size_t)i * BB * 1024; af.out_stride = 1024;
      int sb = SS - 1 - i;
      LstmDirArgs ab;
      ab.W_ih = eWib; ab.W_hh = eWhb; ab.b_ih = ebib; ab.b_hh = ebhb;
      ab.tok = src; ab.tok_stride = SS; ab.tok_idx = sb;
      ab.h_in = hbb[i & 1]; ab.h_out = hbb[(i + 1) & 1]; ab.c = cbb2;
      ab.out_h = enc_outs2 + (size_t)sb * BB * 1024 + HH; ab.out_stride = 1024;
      lstm_step_kernel<<<256, 256, 0, stream>>>(emb, af, ab, 128);
    }

    gemm_tn_kernel<<<dim3(HH / 64, (SS * BB) / 64), 256, 0, stream>>>(
        enc_outs2, aW, abv, keys2, SS * BB, HH, 1024, 0);

    dec_init_kernel<<<BB, 256, 0, stream>>>(hf0b, hb0b, cfb2, cbb2, dhW, dcW, dh0b, dcb2);

    for (int t = 0; t < TT; ++t) {
      LstmDirArgs ad;
      ad.W_ih = cWi; ad.W_hh = cWh; ad.b_ih = cbi; ad.b_hh = cbh;
      ad.tok = tgt; ad.tok_stride = TT; ad.tok_idx = t;
      ad.h_in = dhb[t & 1]; ad.h_out = dhb[(t + 1) & 1]; ad.c = dcb2;
      ad.out_h = dhall2 + (size_t)t * BB * HH; ad.out_stride = HH;
      lstm_step_kernel<<<128, 256, 0, stream>>>(emb, ad, ad, 128);
    }

    attn_kernel<<<TT * BB, 256, 0, stream>>>(keys2, enc_outs2, dhall2, slen, catb2, 0);

    gemm_tn_kernel<<<dim3(HH / 64, (TT * BB) / 64), 256, 0, stream>>>(
        catb2, ccW, ccbv, ccv2, TT * BB, HH, 1536, 1);

    gemm_tn_kernel<<<dim3(VV / 64, (TT * BB) / 64), 256, 0, stream>>>(
        ccv2, oW, obv, out, TT * BB, VV, HH, 2);

    lse_kernel<<<TT * BB, 256, 0, stream>>>(out, stats2);
    lsub_kernel<<<TT * BB, 256, 0, stream>>>(out, stats2);
  }
}